// Round 14
// baseline (53.432 us; speedup 1.0000x reference)
//
#include <hip/hip_runtime.h>
#include <hip/hip_bf16.h>

#define Bdim 4096
#define Ldim 4096
#define Hdim 1024
#define BM 256
#define BN 256
#define BK 64
#define NT (Hdim / BK)   // 16 K-tiles

typedef __attribute__((ext_vector_type(8))) __bf16 bf16x8;
typedef __attribute__((ext_vector_type(4))) float floatx4;
typedef __attribute__((ext_vector_type(16))) float floatx16;

__device__ __forceinline__ unsigned short f2bf(float f) {
  union { __hip_bfloat16 h; unsigned short u; } c;
  c.h = __float2bfloat16(f);
  return c.u;
}

// ---- prep (R10 champion version, unchanged): 2048 blocks x 256 thr.
// blocks [0,1024): W->bf16 + bias, one wave per row, pure shfl reduce.
// blocks [1024,2048): X->bf16, 4 float4/thread.
__global__ __launch_bounds__(256) void prep_kernel(
    const float* __restrict__ X, const float* __restrict__ E,
    const float* __restrict__ W, const float* __restrict__ b,
    unsigned short* __restrict__ Xb, unsigned short* __restrict__ Wb,
    float* __restrict__ bias) {
  const int blk = blockIdx.x;
  const int t = threadIdx.x;
  if (blk < 1024) {
    const int wave = t >> 6;
    const int lane = t & 63;
    const int row = blk * 4 + wave;
    const float4* wrow = reinterpret_cast<const float4*>(W + (size_t)row * Hdim);
    const float4* erow = reinterpret_cast<const float4*>(E + (size_t)row * Hdim);
    ushort4* wbrow = reinterpret_cast<ushort4*>(Wb + (size_t)row * Hdim);
    float dot = 0.f;
#pragma unroll
    for (int j = 0; j < 4; ++j) {
      const int idx = lane + j * 64;
      const float4 wv = wrow[idx];
      const float4 ev = erow[idx];
      ushort4 o;
      o.x = f2bf(wv.x); o.y = f2bf(wv.y); o.z = f2bf(wv.z); o.w = f2bf(wv.w);
      wbrow[idx] = o;
      dot += wv.x * ev.x + wv.y * ev.y + wv.z * ev.z + wv.w * ev.w;
    }
#pragma unroll
    for (int off = 32; off > 0; off >>= 1) dot += __shfl_down(dot, off, 64);
    if (lane == 0) bias[row] = dot + b[row];
  } else {
    const int base = (blk - 1024) * 1024 + t;
    const float4* xs = reinterpret_cast<const float4*>(X);
    ushort4* xd = reinterpret_cast<ushort4*>(Xb);
#pragma unroll
    for (int j = 0; j < 4; ++j) {
      const float4 v = xs[base + j * 256];
      ushort4 o;
      o.x = f2bf(v.x); o.y = f2bf(v.y); o.z = f2bf(v.z); o.w = f2bf(v.w);
      xd[base + j * 256] = o;
    }
  }
}

// ---- C[B,L] = Xb @ Wb^T + bias -----------------------------------------
// R14 = R13 champion (49.36us) with ONE change: MFMA shape 16x16x32 ->
// 32x32x16 (ubench 2382 vs 2075 TF, +15% rate; 32 vs 64 instrs/wave/tile).
// Schedule-iso mapping: per-wave 128x64 = 4mi x 2ni fragments of 32x32,
// 4 K-steps of 16. Quadrant (mi-half h, ni): P0=(h0,ni0) reads af[0-1][*]
// (8) + bf[0][*] (4) = 12 reads; P1=(h1,ni0) reads af[2-3][*] (8);
// P2=(h0,ni1) reads bf[1][*] (4); P3=(h1,ni1) no reads -- IDENTICAL
// read-per-phase counts and A/B liveness to R13 (A fully read by end-P1
// -> A(t+2) stages at P2/P3 legal; B(ni0) at P0, B(ni1) at P2).
// Stage stream / gates / barriers / swizzle: byte-identical to R13.
// Operand layout 32x32x16 bf16: A lane l -> row l&31, k = (l>>5)*8+j
// (generalization of the verified 16x16 pattern); C/D: col=lane&31,
// row=(reg&3)+8*(reg>>2)+4*(lane>>5)  [m74/m101 end-to-end verified].
// Regs: acc 4x2 f32x16 = 128, frags af[4][4]+bf[2][4] = 96 -- same as R13.
// Gate: at P3 outstanding = A(t+1)[4]+B(t+1)[4]+A(t+2)[4]=12; vmcnt(4)
// retires all of t+1, keeps A(t+2) in flight. Tile 14 stages B(15), GATE0.
// Tile 15: no stage/gate. Never vmcnt(0) mid-loop.
// LDS swizzle (T2): 16B-slot s of row r stored at s^(r&7); GLL dest
// linear, global SOURCE pre-swizzled; reads use s = ks*2 + (lane>>5),
// row&7 = lane&7 -> phys slot (ks*2+kh)^(lane&7). Consecutive 8-lane
// groups cover all 8 slots -> conflict-free (same class as R13's
// measured-zero pattern).
__global__ __launch_bounds__(512, 2) void gemm_bias_kernel(
    const unsigned short* __restrict__ A,   // [Bdim][Hdim] bf16 bits
    const unsigned short* __restrict__ Bw,  // [Ldim][Hdim] bf16 bits
    const float* __restrict__ bias,         // [Ldim]
    float* __restrict__ C) {                // [Bdim][Ldim] fp32
  __shared__ __align__(16) unsigned short lds[2][2][BM * BK];  // 128 KB

  const int tid = threadIdx.x;
  const int wave = tid >> 6;
  const int lane = tid & 63;
  const int wm = wave >> 2;   // 0..1  (M half)
  const int wn = wave & 3;    // 0..3  (N quarter)
  const int m_blk = blockIdx.y * BM;
  const int n_blk = blockIdx.x * BN;

  // staging source (pre-swizzled): wave covers rows [wave*8,+8) per GLL
  const int srow = wave * 8 + (lane >> 3);
  const int skofs = ((lane & 7) ^ (lane >> 3)) * 8;
  const unsigned short* gA = A + (size_t)(m_blk + srow) * Hdim + skofs;
  const unsigned short* gB = Bw + (size_t)(n_blk + srow) * Hdim + skofs;

  // fragment read offsets (32x32 layout): row = base + (lane&31),
  // k 16B-slot s = ks*2 + (lane>>5), phys = s ^ (row&7) = s ^ (lane&7)
  const int rl = lane & 31;
  const int kh = lane >> 5;
  int kxs[4];
#pragma unroll
  for (int ks = 0; ks < 4; ++ks) kxs[ks] = ((ks * 2 + kh) ^ (lane & 7)) * 8;
  const int aBase = (wm * 128 + rl) * BK;
  const int bBase = (wn * 64 + rl) * BK;

  floatx16 acc[4][2] = {};
  bf16x8 af[4][4], bfv[2][4];

#define GLL(src, dst)                                                  \
  __builtin_amdgcn_global_load_lds(                                    \
      (const __attribute__((address_space(1))) void*)(src),            \
      (__attribute__((address_space(3))) void*)(dst), 16, 0, 0)

  // stage one half-tile (mat 0=A 1=B, h = row-half) of K-tile kt into buf c
#define STAGE_H(c, mat, h, kt)                                         \
  do {                                                                 \
    const unsigned short* _g = (mat) ? gB : gA;                        \
    GLL(_g + (size_t)((h) * 128) * Hdim + (size_t)(kt) * BK,           \
        &lds[c][mat][((h) * 128 + wave * 8) * BK]);                    \
    GLL(_g + (size_t)((h) * 128 + 64) * Hdim + (size_t)(kt) * BK,      \
        &lds[c][mat][((h) * 128 + 64 + wave * 8) * BK]);               \
  } while (0)

  // read A fragments for mi = lo, lo+1 (all 4 K-steps): 8 ds_read_b128
#define READ_A(c, lo)                                                  \
  do {                                                                 \
    _Pragma("unroll") for (int mi = (lo); mi < (lo) + 2; ++mi)         \
      _Pragma("unroll") for (int ks = 0; ks < 4; ++ks)                 \
        af[mi][ks] = *(const bf16x8*)&lds[c][0][aBase + mi * 32 * BK + kxs[ks]]; \
  } while (0)

  // read B fragments for one ni (all 4 K-steps): 4 ds_read_b128
#define READ_B(c, ni)                                                  \
  do {                                                                 \
    _Pragma("unroll") for (int ks = 0; ks < 4; ++ks)                   \
      bfv[ni][ks] = *(const bf16x8*)&lds[c][1][bBase + (ni) * 32 * BK + kxs[ks]]; \
  } while (0)

  // one quadrant: mi in {M0,M0+1} x one ni x 4 K-steps = 8 MFMA (32x32x16)
#define MFMA_Q(M0, NI)                                                 \
  do {                                                                 \
    __builtin_amdgcn_s_setprio(1);                                     \
    _Pragma("unroll") for (int mi = (M0); mi < (M0) + 2; ++mi)         \
      _Pragma("unroll") for (int ks = 0; ks < 4; ++ks)                 \
        acc[mi][NI] = __builtin_amdgcn_mfma_f32_32x32x16_bf16(         \
            af[mi][ks], bfv[NI][ks], acc[mi][NI], 0, 0, 0);            \
    __builtin_amdgcn_s_setprio(0);                                     \
  } while (0)

#define BAR __builtin_amdgcn_s_barrier()
#define GATE4 asm volatile("s_waitcnt vmcnt(4)\n\ts_barrier" ::: "memory")
#define GATE0 asm volatile("s_waitcnt vmcnt(0)\n\ts_barrier" ::: "memory")

  // DO_B: stage B(kt+1)->o at P0/P1.  DO_A: stage A(kt+2)->c at P2/P3.
#define TILE_BODY(c, o, kt, DO_B, DO_A, GATE)                          \
  do {                                                                 \
    /* P0: quadrant (mi 0-1, ni 0) */                                  \
    if (DO_B) STAGE_H(o, 1, 0, (kt) + 1);                              \
    READ_A(c, 0);                                                      \
    READ_B(c, 0);                                                      \
    BAR;                                                               \
    MFMA_Q(0, 0);                                                      \
    /* P1: quadrant (mi 2-3, ni 0) */                                  \
    if (DO_B) STAGE_H(o, 1, 1, (kt) + 1);                              \
    READ_A(c, 2);                                                      \
    BAR;                                                               \
    MFMA_Q(2, 0);                                                      \
    BAR;  /* collective: all af reads of buf c complete -> c.A free */ \
    /* P2: quadrant (mi 0-1, ni 1) */                                  \
    if (DO_A) STAGE_H(c, 0, 0, (kt) + 2);                              \
    READ_B(c, 1);                                                      \
    BAR;                                                               \
    MFMA_Q(0, 1);                                                      \
    BAR;  /* collective: all reads of buf c complete */                \
    /* P3: quadrant (mi 2-3, ni 1) */                                  \
    if (DO_A) STAGE_H(c, 0, 1, (kt) + 2);                              \
    GATE;                                                              \
    MFMA_Q(2, 1);                                                      \
  } while (0)

  // prologue: tile 0 fully + tile 1 A halves (12 GLLs), gate to 4
  STAGE_H(0, 0, 0, 0);
  STAGE_H(0, 0, 1, 0);
  STAGE_H(0, 1, 0, 0);
  STAGE_H(0, 1, 1, 0);
  STAGE_H(1, 0, 0, 1);
  STAGE_H(1, 0, 1, 1);
  GATE4;

#pragma unroll 1
  for (int t = 0; t < NT - 2; t += 2) {
    TILE_BODY(0, 1, t, 1, 1, GATE4);
    TILE_BODY(1, 0, t + 1, 1, 1, GATE4);
  }
  // tile NT-2 (buf 0): stages B(NT-1)->buf1; no A stage; GATE0 drains
  // A(15)+B(15) (B(15) issued 2 phases earlier).
  TILE_BODY(0, 1, NT - 2, 1, 0, GATE0);
  // tile NT-1 (buf 1): all data resident & retired; no stages, no gate.
  TILE_BODY(1, 0, NT - 1, 0, 0, (void)0);

#undef GLL
#undef STAGE_H
#undef READ_A
#undef READ_B
#undef MFMA_Q
#undef BAR
#undef GATE4
#undef GATE0
#undef TILE_BODY

  // epilogue: 32x32 C/D layout col=lane&31, row=(reg&3)+8*(reg>>2)+4*kh
  // [m74/m101-verified]
  const int col0 = n_blk + wn * 64 + rl;
#pragma unroll
  for (int ni = 0; ni < 2; ++ni) {
    const int colN = col0 + ni * 32;
    const float bs = bias[colN];
#pragma unroll
    for (int mi = 0; mi < 4; ++mi) {
      const int rowbase = m_blk + wm * 128 + mi * 32 + 4 * kh;
      float* cp = C + (size_t)rowbase * Ldim + colN;
      const floatx16 v = acc[mi][ni];
#pragma unroll
      for (int reg = 0; reg < 16; ++reg) {
        const int rofs = (reg & 3) + 8 * (reg >> 2);
        cp[(size_t)rofs * Ldim] = v[reg] + bs;
      }
    }
  }
}

extern "C" void kernel_launch(void* const* d_in, const int* in_sizes, int n_in,
                              void* d_out, int out_size, void* d_ws, size_t ws_size,
                              hipStream_t stream) {
  const float* X = (const float*)d_in[0];  // bert_output [B,H]
  const float* E = (const float*)d_in[1];  // label_embed [L,H]
  const float* W = (const float*)d_in[2];  // W [L,H]
  const float* b = (const float*)d_in[3];  // b [L]
  // d_in[4] = labels, unused by the reference output.
  float* out = (float*)d_out;

  unsigned short* Xb = (unsigned short*)d_ws;                 // 8 MB
  unsigned short* Wb = Xb + (size_t)Bdim * Hdim;              // 8 MB
  float* bias = (float*)(Wb + (size_t)Ldim * Hdim);           // 16 KB

  prep_kernel<<<2048, 256, 0, stream>>>(X, E, W, b, Xb, Wb, bias);
  dim3 grid(Ldim / BN, Bdim / BM);
  gemm_bias_kernel<<<grid, 512, 0, stream>>>(Xb, Wb, bias, out);
}

// Round 16
// 48.341 us; speedup vs baseline: 1.1053x; 1.1053x over previous
//
#include <hip/hip_runtime.h>
#include <hip/hip_bf16.h>

#define Bdim 4096
#define Ldim 4096
#define Hdim 1024
#define BM 256
#define BN 256
#define BK 64
#define NT (Hdim / BK)   // 16 K-tiles

typedef __attribute__((ext_vector_type(8))) __bf16 bf16x8;
typedef __attribute__((ext_vector_type(4))) float floatx4;

__device__ __forceinline__ unsigned short f2bf(float f) {
  union { __hip_bfloat16 h; unsigned short u; } c;
  c.h = __float2bfloat16(f);
  return c.u;
}

// ---- prep (R10 champion version, unchanged): 2048 blocks x 256 thr.
// blocks [0,1024): W->bf16 + bias, one wave per row, pure shfl reduce.
// blocks [1024,2048): X->bf16, 4 float4/thread.
__global__ __launch_bounds__(256) void prep_kernel(
    const float* __restrict__ X, const float* __restrict__ E,
    const float* __restrict__ W, const float* __restrict__ b,
    unsigned short* __restrict__ Xb, unsigned short* __restrict__ Wb,
    float* __restrict__ bias) {
  const int blk = blockIdx.x;
  const int t = threadIdx.x;
  if (blk < 1024) {
    const int wave = t >> 6;
    const int lane = t & 63;
    const int row = blk * 4 + wave;
    const float4* wrow = reinterpret_cast<const float4*>(W + (size_t)row * Hdim);
    const float4* erow = reinterpret_cast<const float4*>(E + (size_t)row * Hdim);
    ushort4* wbrow = reinterpret_cast<ushort4*>(Wb + (size_t)row * Hdim);
    float dot = 0.f;
#pragma unroll
    for (int j = 0; j < 4; ++j) {
      const int idx = lane + j * 64;
      const float4 wv = wrow[idx];
      const float4 ev = erow[idx];
      ushort4 o;
      o.x = f2bf(wv.x); o.y = f2bf(wv.y); o.z = f2bf(wv.z); o.w = f2bf(wv.w);
      wbrow[idx] = o;
      dot += wv.x * ev.x + wv.y * ev.y + wv.z * ev.z + wv.w * ev.w;
    }
#pragma unroll
    for (int off = 32; off > 0; off >>= 1) dot += __shfl_down(dot, off, 64);
    if (lane == 0) bias[row] = dot + b[row];
  } else {
    const int base = (blk - 1024) * 1024 + t;
    const float4* xs = reinterpret_cast<const float4*>(X);
    ushort4* xd = reinterpret_cast<ushort4*>(Xb);
#pragma unroll
    for (int j = 0; j < 4; ++j) {
      const float4 v = xs[base + j * 256];
      ushort4 o;
      o.x = f2bf(v.x); o.y = f2bf(v.y); o.z = f2bf(v.z); o.w = f2bf(v.w);
      xd[base + j * 256] = o;
    }
  }
}

// ---- C[B,L] = Xb @ Wb^T + bias -----------------------------------------
// R16 = R15 resubmitted (R15 run died to container failure, no data).
// R15 = R13 champion (49.36us; 16x16x32 MFMA -- R14's 32x32x16 swap
// regressed via 3.15M LDS bank conflicts, reverted) with ONE change:
// EPILOGUE STORE ORDER row-major. R13 issued same-row 64B segments (cols
// +0/+16/+32/+48) ~30 stores apart (ni-outer) -> L2 couldn't combine ->
// WRITE_SIZE 71.2MB vs 64 ideal. Now each row's 4 segments (contiguous
// 256B per wave) issue back-to-back. Same addresses/values, issue-order
// only. (R14's 32x32 layout proved 128B-segment stores -> exactly 64MB.)
// Loop structure (byte-identical to R13):
//   P0: [stage Bh0(t+1)->o] reads A(0-3)+B(0-1); BAR; 16 MFMA
//   P1: [stage Bh1(t+1)->o] reads A(4-7);        BAR; 16 MFMA; BAR
//   P2: [stage Ah0(t+2)->c] reads B(2-3);        BAR; 16 MFMA; BAR
//   P3: [stage Ah1(t+2)->c] GATE vmcnt(4)+BAR;        16 MFMA
// No per-phase lgkmcnt(0) drains (R13: compiler emits minimal counted
// lgkmcnt for the visible ds_read->MFMA deps; manual drain was -0.3us).
// WAR: all af reads of c retired before P1's post-MFMA BAR -> A(t+2) into
// c.A at P2/P3 safe; o.B last read at t-1's P2, certified by t-1 P3 gate.
// Gate: at P3 outstanding = A(t+1)[4]+B(t+1)[4]+A(t+2)[4]=12; vmcnt(4)
// retires all of t+1, keeps A(t+2) in flight. Tile 14 stages B(15), GATE0.
// Tile 15: no stage/gate. Never vmcnt(0) mid-loop.
// LDS swizzle (T2, conflicts=0 measured): 16B-slot ks of row r at ks^(r&7);
// GLL dest linear, global SOURCE pre-swizzled, reads same XOR.
__global__ __launch_bounds__(512, 2) void gemm_bias_kernel(
    const unsigned short* __restrict__ A,   // [Bdim][Hdim] bf16 bits
    const unsigned short* __restrict__ Bw,  // [Ldim][Hdim] bf16 bits
    const float* __restrict__ bias,         // [Ldim]
    float* __restrict__ C) {                // [Bdim][Ldim] fp32
  __shared__ __align__(16) unsigned short lds[2][2][BM * BK];  // 128 KB

  const int tid = threadIdx.x;
  const int wave = tid >> 6;
  const int lane = tid & 63;
  const int wm = wave >> 2;   // 0..1  (M half)
  const int wn = wave & 3;    // 0..3  (N quarter)
  const int m_blk = blockIdx.y * BM;
  const int n_blk = blockIdx.x * BN;

  // staging source (pre-swizzled): wave covers rows [wave*8,+8) per GLL
  const int srow = wave * 8 + (lane >> 3);
  const int skofs = ((lane & 7) ^ (lane >> 3)) * 8;
  const unsigned short* gA = A + (size_t)(m_blk + srow) * Hdim + skofs;
  const unsigned short* gB = Bw + (size_t)(n_blk + srow) * Hdim + skofs;

  // fragment read offsets (swizzled): row = base+fr, k 16B-slot = ksl*4+fq
  const int fr = lane & 15;
  const int fq = lane >> 4;
  const int kx0 = ((fq) ^ (fr & 7)) * 8;        // k 0..31
  const int kx1 = ((4 + fq) ^ (fr & 7)) * 8;    // k 32..63
  const int aBase = (wm * 128 + fr) * BK;
  const int bBase = (wn * 64 + fr) * BK;

  floatx4 acc[8][4] = {};
  bf16x8 af[8][2], bfv[4][2];

#define GLL(src, dst)                                                  \
  __builtin_amdgcn_global_load_lds(                                    \
      (const __attribute__((address_space(1))) void*)(src),            \
      (__attribute__((address_space(3))) void*)(dst), 16, 0, 0)

  // stage one half-tile (mat 0=A 1=B, h = row-half) of K-tile kt into buf c
#define STAGE_H(c, mat, h, kt)                                         \
  do {                                                                 \
    const unsigned short* _g = (mat) ? gB : gA;                        \
    GLL(_g + (size_t)((h) * 128) * Hdim + (size_t)(kt) * BK,           \
        &lds[c][mat][((h) * 128 + wave * 8) * BK]);                    \
    GLL(_g + (size_t)((h) * 128 + 64) * Hdim + (size_t)(kt) * BK,      \
        &lds[c][mat][((h) * 128 + 64 + wave * 8) * BK]);               \
  } while (0)

#define READ_A(c, lo)                                                  \
  do {                                                                 \
    _Pragma("unroll") for (int mi = (lo); mi < (lo) + 4; ++mi) {       \
      af[mi][0] = *(const bf16x8*)&lds[c][0][aBase + mi * 16 * BK + kx0]; \
      af[mi][1] = *(const bf16x8*)&lds[c][0][aBase + mi * 16 * BK + kx1]; \
    }                                                                  \
  } while (0)

#define READ_B(c, lo)                                                  \
  do {                                                                 \
    _Pragma("unroll") for (int ni = (lo); ni < (lo) + 2; ++ni) {       \
      bfv[ni][0] = *(const bf16x8*)&lds[c][1][bBase + ni * 16 * BK + kx0]; \
      bfv[ni][1] = *(const bf16x8*)&lds[c][1][bBase + ni * 16 * BK + kx1]; \
    }                                                                  \
  } while (0)

#define MFMA_Q(M0, N0)                                                 \
  do {                                                                 \
    __builtin_amdgcn_s_setprio(1);                                     \
    _Pragma("unroll") for (int mi = (M0); mi < (M0) + 4; ++mi)         \
      _Pragma("unroll") for (int ni = (N0); ni < (N0) + 2; ++ni) {     \
        acc[mi][ni] = __builtin_amdgcn_mfma_f32_16x16x32_bf16(         \
            af[mi][0], bfv[ni][0], acc[mi][ni], 0, 0, 0);              \
        acc[mi][ni] = __builtin_amdgcn_mfma_f32_16x16x32_bf16(         \
            af[mi][1], bfv[ni][1], acc[mi][ni], 0, 0, 0);              \
      }                                                                \
    __builtin_amdgcn_s_setprio(0);                                     \
  } while (0)

#define BAR __builtin_amdgcn_s_barrier()
#define GATE4 asm volatile("s_waitcnt vmcnt(4)\n\ts_barrier" ::: "memory")
#define GATE0 asm volatile("s_waitcnt vmcnt(0)\n\ts_barrier" ::: "memory")

  // DO_B: stage B(kt+1)->o at P0/P1.  DO_A: stage A(kt+2)->c at P2/P3.
#define TILE_BODY(c, o, kt, DO_B, DO_A, GATE)                          \
  do {                                                                 \
    /* P0 */                                                           \
    if (DO_B) STAGE_H(o, 1, 0, (kt) + 1);                              \
    READ_A(c, 0);                                                      \
    READ_B(c, 0);                                                      \
    BAR;                                                               \
    MFMA_Q(0, 0);                                                      \
    /* P1 */                                                           \
    if (DO_B) STAGE_H(o, 1, 1, (kt) + 1);                              \
    READ_A(c, 4);                                                      \
    BAR;                                                               \
    MFMA_Q(4, 0);                                                      \
    BAR;  /* collective: all af reads of buf c complete -> c.A free */ \
    /* P2 */                                                           \
    if (DO_A) STAGE_H(c, 0, 0, (kt) + 2);                              \
    READ_B(c, 2);                                                      \
    BAR;                                                               \
    MFMA_Q(0, 2);                                                      \
    BAR;  /* collective: all reads of buf c complete */                \
    /* P3 */                                                           \
    if (DO_A) STAGE_H(c, 0, 1, (kt) + 2);                              \
    GATE;                                                              \
    MFMA_Q(4, 2);                                                      \
  } while (0)

  // prologue: tile 0 fully + tile 1 A halves (12 GLLs), gate to 4
  STAGE_H(0, 0, 0, 0);
  STAGE_H(0, 0, 1, 0);
  STAGE_H(0, 1, 0, 0);
  STAGE_H(0, 1, 1, 0);
  STAGE_H(1, 0, 0, 1);
  STAGE_H(1, 0, 1, 1);
  GATE4;

#pragma unroll 1
  for (int t = 0; t < NT - 2; t += 2) {
    TILE_BODY(0, 1, t, 1, 1, GATE4);
    TILE_BODY(1, 0, t + 1, 1, 1, GATE4);
  }
  // tile NT-2 (buf 0): stages B(NT-1)->buf1; no A stage; GATE0 drains
  // A(15)+B(15) (B(15) issued 2 phases earlier).
  TILE_BODY(0, 1, NT - 2, 1, 0, GATE0);
  // tile NT-1 (buf 1): all data resident & retired; no stages, no gate.
  TILE_BODY(1, 0, NT - 1, 0, 0, (void)0);

#undef GLL
#undef STAGE_H
#undef READ_A
#undef READ_B
#undef MFMA_Q
#undef BAR
#undef GATE4
#undef GATE0
#undef TILE_BODY

  // epilogue: C/D layout col=lane&15, row=(lane>>4)*4+reg  [m89-verified]
  // R15: row-major store order -- for each C row, the wave's four 64B
  // segments (cols +0/+16/+32/+48, contiguous 256B) issue back-to-back
  // so L2 write-combines them (R13's ni-outer order scattered them).
  const int col0 = n_blk + wn * 64 + fr;
  const int row0 = m_blk + wm * 128 + fq * 4;
  float bs[4];
#pragma unroll
  for (int ni = 0; ni < 4; ++ni) bs[ni] = bias[col0 + ni * 16];
#pragma unroll
  for (int mi = 0; mi < 8; ++mi) {
#pragma unroll
    for (int j = 0; j < 4; ++j) {
      float* rowp = C + (size_t)(row0 + mi * 16 + j) * Ldim + col0;
#pragma unroll
      for (int ni = 0; ni < 4; ++ni)
        rowp[ni * 16] = acc[mi][ni][j] + bs[ni];
    }
  }
}

extern "C" void kernel_launch(void* const* d_in, const int* in_sizes, int n_in,
                              void* d_out, int out_size, void* d_ws, size_t ws_size,
                              hipStream_t stream) {
  const float* X = (const float*)d_in[0];  // bert_output [B,H]
  const float* E = (const float*)d_in[1];  // label_embed [L,H]
  const float* W = (const float*)d_in[2];  // W [L,H]
  const float* b = (const float*)d_in[3];  // b [L]
  // d_in[4] = labels, unused by the reference output.
  float* out = (float*)d_out;

  unsigned short* Xb = (unsigned short*)d_ws;                 // 8 MB
  unsigned short* Wb = Xb + (size_t)Bdim * Hdim;              // 8 MB
  float* bias = (float*)(Wb + (size_t)Ldim * Hdim);           // 16 KB

  prep_kernel<<<2048, 256, 0, stream>>>(X, E, W, b, Xb, Wb, bias);
  dim3 grid(Ldim / BN, Bdim / BM);
  gemm_bias_kernel<<<grid, 512, 0, stream>>>(Xb, Wb, bias, out);
}

// Round 17
// 48.244 us; speedup vs baseline: 1.1075x; 1.0020x over previous
//
#include <hip/hip_runtime.h>
#include <hip/hip_bf16.h>

#define Bdim 4096
#define Ldim 4096
#define Hdim 1024
#define BM 256
#define BN 256
#define BK 64
#define NT (Hdim / BK)   // 16 K-tiles

typedef __attribute__((ext_vector_type(8))) __bf16 bf16x8;
typedef __attribute__((ext_vector_type(4))) float floatx4;

__device__ __forceinline__ unsigned short f2bf(float f) {
  union { __hip_bfloat16 h; unsigned short u; } c;
  c.h = __float2bfloat16(f);
  return c.u;
}

// ---- prep (R10 champion version, unchanged): 2048 blocks x 256 thr.
// blocks [0,1024): W->bf16 + bias, one wave per row, pure shfl reduce.
// blocks [1024,2048): X->bf16, 4 float4/thread.
__global__ __launch_bounds__(256) void prep_kernel(
    const float* __restrict__ X, const float* __restrict__ E,
    const float* __restrict__ W, const float* __restrict__ b,
    unsigned short* __restrict__ Xb, unsigned short* __restrict__ Wb,
    float* __restrict__ bias) {
  const int blk = blockIdx.x;
  const int t = threadIdx.x;
  if (blk < 1024) {
    const int wave = t >> 6;
    const int lane = t & 63;
    const int row = blk * 4 + wave;
    const float4* wrow = reinterpret_cast<const float4*>(W + (size_t)row * Hdim);
    const float4* erow = reinterpret_cast<const float4*>(E + (size_t)row * Hdim);
    ushort4* wbrow = reinterpret_cast<ushort4*>(Wb + (size_t)row * Hdim);
    float dot = 0.f;
#pragma unroll
    for (int j = 0; j < 4; ++j) {
      const int idx = lane + j * 64;
      const float4 wv = wrow[idx];
      const float4 ev = erow[idx];
      ushort4 o;
      o.x = f2bf(wv.x); o.y = f2bf(wv.y); o.z = f2bf(wv.z); o.w = f2bf(wv.w);
      wbrow[idx] = o;
      dot += wv.x * ev.x + wv.y * ev.y + wv.z * ev.z + wv.w * ev.w;
    }
#pragma unroll
    for (int off = 32; off > 0; off >>= 1) dot += __shfl_down(dot, off, 64);
    if (lane == 0) bias[row] = dot + b[row];
  } else {
    const int base = (blk - 1024) * 1024 + t;
    const float4* xs = reinterpret_cast<const float4*>(X);
    ushort4* xd = reinterpret_cast<ushort4*>(Xb);
#pragma unroll
    for (int j = 0; j < 4; ++j) {
      const float4 v = xs[base + j * 256];
      ushort4 o;
      o.x = f2bf(v.x); o.y = f2bf(v.y); o.z = f2bf(v.z); o.w = f2bf(v.w);
      xd[base + j * 256] = o;
    }
  }
}

// ---- C[B,L] = Xb @ Wb^T + bias -----------------------------------------
// R17 = R16 champion (48.34us) with ONE change: P0 READ ORDER B-first.
// LDS returns complete in issue order; R16 issued 8 A-reads then 4 B-reads,
// but the first MFMA consumes af[0]+bfv[0] (the 9th/10th-issued reads) ->
// every tile's first MFMA stalled behind ~10/12 reads. B-first makes it
// eligible after ~5, letting the compiler's counted lgkmcnt (unlocked in
// R13) overlap the remaining A-reads under the MFMA cluster. Same loads,
// same addresses -- issue order only.
// History: R16 row-major epilogue (WRITE 71.2->65.9MB, -1.0us); R13 no
// manual lgkm drains; R14 32x32 MFMA regressed (3.15M bank conflicts).
// Loop structure (otherwise byte-identical):
//   P0: [stage Bh0(t+1)->o] reads B(0-1),A(0-3); BAR; 16 MFMA
//   P1: [stage Bh1(t+1)->o] reads A(4-7);        BAR; 16 MFMA; BAR
//   P2: [stage Ah0(t+2)->c] reads B(2-3);        BAR; 16 MFMA; BAR
//   P3: [stage Ah1(t+2)->c] GATE vmcnt(4)+BAR;        16 MFMA
// WAR: all af reads of c retired before P1's post-MFMA BAR -> A(t+2) into
// c.A at P2/P3 safe; o.B last read at t-1's P2, certified by t-1 P3 gate.
// Gate: at P3 outstanding = A(t+1)[4]+B(t+1)[4]+A(t+2)[4]=12; vmcnt(4)
// retires all of t+1, keeps A(t+2) in flight. Tile 14 stages B(15), GATE0.
// Tile 15: no stage/gate. Never vmcnt(0) mid-loop.
// LDS swizzle (T2, conflicts=0 measured): 16B-slot ks of row r at ks^(r&7);
// GLL dest linear, global SOURCE pre-swizzled, reads same XOR.
__global__ __launch_bounds__(512, 2) void gemm_bias_kernel(
    const unsigned short* __restrict__ A,   // [Bdim][Hdim] bf16 bits
    const unsigned short* __restrict__ Bw,  // [Ldim][Hdim] bf16 bits
    const float* __restrict__ bias,         // [Ldim]
    float* __restrict__ C) {                // [Bdim][Ldim] fp32
  __shared__ __align__(16) unsigned short lds[2][2][BM * BK];  // 128 KB

  const int tid = threadIdx.x;
  const int wave = tid >> 6;
  const int lane = tid & 63;
  const int wm = wave >> 2;   // 0..1  (M half)
  const int wn = wave & 3;    // 0..3  (N quarter)
  const int m_blk = blockIdx.y * BM;
  const int n_blk = blockIdx.x * BN;

  // staging source (pre-swizzled): wave covers rows [wave*8,+8) per GLL
  const int srow = wave * 8 + (lane >> 3);
  const int skofs = ((lane & 7) ^ (lane >> 3)) * 8;
  const unsigned short* gA = A + (size_t)(m_blk + srow) * Hdim + skofs;
  const unsigned short* gB = Bw + (size_t)(n_blk + srow) * Hdim + skofs;

  // fragment read offsets (swizzled): row = base+fr, k 16B-slot = ksl*4+fq
  const int fr = lane & 15;
  const int fq = lane >> 4;
  const int kx0 = ((fq) ^ (fr & 7)) * 8;        // k 0..31
  const int kx1 = ((4 + fq) ^ (fr & 7)) * 8;    // k 32..63
  const int aBase = (wm * 128 + fr) * BK;
  const int bBase = (wn * 64 + fr) * BK;

  floatx4 acc[8][4] = {};
  bf16x8 af[8][2], bfv[4][2];

#define GLL(src, dst)                                                  \
  __builtin_amdgcn_global_load_lds(                                    \
      (const __attribute__((address_space(1))) void*)(src),            \
      (__attribute__((address_space(3))) void*)(dst), 16, 0, 0)

  // stage one half-tile (mat 0=A 1=B, h = row-half) of K-tile kt into buf c
#define STAGE_H(c, mat, h, kt)                                         \
  do {                                                                 \
    const unsigned short* _g = (mat) ? gB : gA;                        \
    GLL(_g + (size_t)((h) * 128) * Hdim + (size_t)(kt) * BK,           \
        &lds[c][mat][((h) * 128 + wave * 8) * BK]);                    \
    GLL(_g + (size_t)((h) * 128 + 64) * Hdim + (size_t)(kt) * BK,      \
        &lds[c][mat][((h) * 128 + 64 + wave * 8) * BK]);               \
  } while (0)

#define READ_A(c, lo)                                                  \
  do {                                                                 \
    _Pragma("unroll") for (int mi = (lo); mi < (lo) + 4; ++mi) {       \
      af[mi][0] = *(const bf16x8*)&lds[c][0][aBase + mi * 16 * BK + kx0]; \
      af[mi][1] = *(const bf16x8*)&lds[c][0][aBase + mi * 16 * BK + kx1]; \
    }                                                                  \
  } while (0)

#define READ_B(c, lo)                                                  \
  do {                                                                 \
    _Pragma("unroll") for (int ni = (lo); ni < (lo) + 2; ++ni) {       \
      bfv[ni][0] = *(const bf16x8*)&lds[c][1][bBase + ni * 16 * BK + kx0]; \
      bfv[ni][1] = *(const bf16x8*)&lds[c][1][bBase + ni * 16 * BK + kx1]; \
    }                                                                  \
  } while (0)

#define MFMA_Q(M0, N0)                                                 \
  do {                                                                 \
    __builtin_amdgcn_s_setprio(1);                                     \
    _Pragma("unroll") for (int mi = (M0); mi < (M0) + 4; ++mi)         \
      _Pragma("unroll") for (int ni = (N0); ni < (N0) + 2; ++ni) {     \
        acc[mi][ni] = __builtin_amdgcn_mfma_f32_16x16x32_bf16(         \
            af[mi][0], bfv[ni][0], acc[mi][ni], 0, 0, 0);              \
        acc[mi][ni] = __builtin_amdgcn_mfma_f32_16x16x32_bf16(         \
            af[mi][1], bfv[ni][1], acc[mi][ni], 0, 0, 0);              \
      }                                                                \
    __builtin_amdgcn_s_setprio(0);                                     \
  } while (0)

#define BAR __builtin_amdgcn_s_barrier()
#define GATE4 asm volatile("s_waitcnt vmcnt(4)\n\ts_barrier" ::: "memory")
#define GATE0 asm volatile("s_waitcnt vmcnt(0)\n\ts_barrier" ::: "memory")

  // DO_B: stage B(kt+1)->o at P0/P1.  DO_A: stage A(kt+2)->c at P2/P3.
#define TILE_BODY(c, o, kt, DO_B, DO_A, GATE)                          \
  do {                                                                 \
    /* P0: B-reads FIRST (first MFMA needs bfv[0]+af[0]; in-order LDS   \
       completion makes it eligible after ~5 reads instead of ~10) */  \
    if (DO_B) STAGE_H(o, 1, 0, (kt) + 1);                              \
    READ_B(c, 0);                                                      \
    READ_A(c, 0);                                                      \
    BAR;                                                               \
    MFMA_Q(0, 0);                                                      \
    /* P1 */                                                           \
    if (DO_B) STAGE_H(o, 1, 1, (kt) + 1);                              \
    READ_A(c, 4);                                                      \
    BAR;                                                               \
    MFMA_Q(4, 0);                                                      \
    BAR;  /* collective: all af reads of buf c complete -> c.A free */ \
    /* P2 */                                                           \
    if (DO_A) STAGE_H(c, 0, 0, (kt) + 2);                              \
    READ_B(c, 2);                                                      \
    BAR;                                                               \
    MFMA_Q(0, 2);                                                      \
    BAR;  /* collective: all reads of buf c complete */                \
    /* P3 */                                                           \
    if (DO_A) STAGE_H(c, 0, 1, (kt) + 2);                              \
    GATE;                                                              \
    MFMA_Q(4, 2);                                                      \
  } while (0)

  // prologue: tile 0 fully + tile 1 A halves (12 GLLs), gate to 4
  STAGE_H(0, 0, 0, 0);
  STAGE_H(0, 0, 1, 0);
  STAGE_H(0, 1, 0, 0);
  STAGE_H(0, 1, 1, 0);
  STAGE_H(1, 0, 0, 1);
  STAGE_H(1, 0, 1, 1);
  GATE4;

#pragma unroll 1
  for (int t = 0; t < NT - 2; t += 2) {
    TILE_BODY(0, 1, t, 1, 1, GATE4);
    TILE_BODY(1, 0, t + 1, 1, 1, GATE4);
  }
  // tile NT-2 (buf 0): stages B(NT-1)->buf1; no A stage; GATE0 drains
  // A(15)+B(15) (B(15) issued 2 phases earlier).
  TILE_BODY(0, 1, NT - 2, 1, 0, GATE0);
  // tile NT-1 (buf 1): all data resident & retired; no stages, no gate.
  TILE_BODY(1, 0, NT - 1, 0, 0, (void)0);

#undef GLL
#undef STAGE_H
#undef READ_A
#undef READ_B
#undef MFMA_Q
#undef BAR
#undef GATE4
#undef GATE0
#undef TILE_BODY

  // epilogue: C/D layout col=lane&15, row=(lane>>4)*4+reg  [m89-verified]
  // R16: row-major store order -- each C row's four 64B segments (cols
  // +0/+16/+32/+48, contiguous 256B per wave) issue back-to-back so L2
  // write-combines them. Measured: WRITE_SIZE 71.2 -> 65.9 MB, -1.0us.
  const int col0 = n_blk + wn * 64 + fr;
  const int row0 = m_blk + wm * 128 + fq * 4;
  float bs[4];
#pragma unroll
  for (int ni = 0; ni < 4; ++ni) bs[ni] = bias[col0 + ni * 16];
#pragma unroll
  for (int mi = 0; mi < 8; ++mi) {
#pragma unroll
    for (int j = 0; j < 4; ++j) {
      float* rowp = C + (size_t)(row0 + mi * 16 + j) * Ldim + col0;
#pragma unroll
      for (int ni = 0; ni < 4; ++ni)
        rowp[ni * 16] = acc[mi][ni][j] + bs[ni];
    }
  }
}

extern "C" void kernel_launch(void* const* d_in, const int* in_sizes, int n_in,
                              void* d_out, int out_size, void* d_ws, size_t ws_size,
                              hipStream_t stream) {
  const float* X = (const float*)d_in[0];  // bert_output [B,H]
  const float* E = (const float*)d_in[1];  // label_embed [L,H]
  const float* W = (const float*)d_in[2];  // W [L,H]
  const float* b = (const float*)d_in[3];  // b [L]
  // d_in[4] = labels, unused by the reference output.
  float* out = (float*)d_out;

  unsigned short* Xb = (unsigned short*)d_ws;                 // 8 MB
  unsigned short* Wb = Xb + (size_t)Bdim * Hdim;              // 8 MB
  float* bias = (float*)(Wb + (size_t)Ldim * Hdim);           // 16 KB

  prep_kernel<<<2048, 256, 0, stream>>>(X, E, W, b, Xb, Wb, bias);
  dim3 grid(Ldim / BN, Bdim / BM);
  gemm_bias_kernel<<<grid, 512, 0, stream>>>(Xb, Wb, bias, out);
}